// Round 9
// baseline (260.192 us; speedup 1.0000x reference)
//
#include <hip/hip_runtime.h>
#include <hip/hip_bf16.h>

// Flash-style block attention, MI355X gfx950. Round 13.
// R12 lesson: cutting 33% MFMA / 25% LDS / 90 VALU ops gained 2% -> kernel
// is latency-bound at 4 waves/SIMD lockstep. Only lever left: occupancy.
// Third run at 3 WGs/CU (cap ~84 regs), now with the state actually small
// enough: R12 already dropped V_lo (the R10 overflow); R13 additionally:
//  - Direct-to-global epilogue: ctx^T frags are 16B-contiguous in d ->
//    f32x4 stores straight to out (16 rows x 64B segments, L2 merges).
//    Removes the [128][68] LDS bounce + 2 barriers + its LDS footprint.
//  - Single 27904B buffer (K_hi|K_lo|V|mask), 2 barriers/chunk; masks
//    staged to LDS by lanes<64, read as broadcast f32x4 per-km transient.
//  - No reg prefetch; staging latency is covered by 6 waves/SIMD TLP.
//  - Phase peaks: QK ~64, softmax ~66, stage ~56 VGPR+AGPR(32) ~= 82-84.
//  - Two-pass QK kept (8-reg K transients), (512,6) bound.
// Predicted: WRITE=65536KB exactly (no spill; >70MB = failed), VGPR ~52,
// Occ ~58%, dur ~78-84us/dispatch, MfmaUtil ~22, VALU ~40.

typedef __attribute__((ext_vector_type(8))) short bf16x8;
typedef __attribute__((ext_vector_type(4))) short bf16x4;
typedef __attribute__((ext_vector_type(4))) float f32x4;

#define MFMA32(A, B, C) __builtin_amdgcn_mfma_f32_16x16x32_bf16((A), (B), (C), 0, 0, 0)
#define MFMA16(A, B, C) __builtin_amdgcn_mfma_f32_16x16x16bf16_1k((A), (B), (C), 0, 0, 0)

__device__ __forceinline__ unsigned int cvt_pk(float a, float b) {
    __hip_bfloat162 h = __float22bfloat162_rn(float2{a, b});
    union { __hip_bfloat162 h; unsigned int u; } c;
    c.h = h;
    return c.u;
}
__device__ __forceinline__ void split2(float a, float b, unsigned int& hi, unsigned int& lo) {
    unsigned int h = cvt_pk(a, b);
    float ra = a - __uint_as_float(h << 16);
    float rb = b - __uint_as_float(h & 0xFFFF0000u);
    hi = h;
    lo = cvt_pk(ra, rb);
}
__device__ __forceinline__ void split8v(f32x4 a, f32x4 b, bf16x8& hi, bf16x8& lo) {
    union { bf16x8 v; unsigned int w[4]; } H, L;
    split2(a[0], a[1], H.w[0], L.w[0]);
    split2(a[2], a[3], H.w[1], L.w[1]);
    split2(b[0], b[1], H.w[2], L.w[2]);
    split2(b[2], b[3], H.w[3], L.w[3]);
    hi = H.v; lo = L.v;
}

// LDS: K_hi [64][72] hw (9216) | K_lo [64][72] hw (9216) | V^T [64][72] hw
// (9216) | mask*log2e [64] f32 (256) = 27904 B total. No epilogue scratch.
#define LDS_BYTES 27904

#define LOG2E 1.44269504f
#define QSCALE 0.180336880f  /* 0.125 * log2(e) */
#define DEFER_THR 8.0f

__global__ __launch_bounds__(512, 6) void block_attn_kernel(
    const float* __restrict__ q, const float* __restrict__ k,
    const float* __restrict__ v, const float* __restrict__ amask,
    const float* __restrict__ gk, const float* __restrict__ gv,
    const float* __restrict__ gmask, float* __restrict__ out) {
    constexpr int Hh = 16, Tt = 4096, Gg = 128;

    __shared__ __align__(16) unsigned char lds[LDS_BYTES];
    float* m_lds = (float*)(lds + 27648);  // [64] mask * log2e

    const int blk = blockIdx.x;
    const int bh  = blockIdx.z * Hh + blockIdx.y;
    const int tid  = threadIdx.x;
    const int lane = tid & 63;
    const int wv   = tid >> 6;      // 0..7, wave owns q-rows [wv*16, wv*16+16)
    const int c15  = lane & 15;
    const int quad = lane >> 4;

    const float* qptr = q + ((size_t)bh * Tt + blk * 128) * 64;
    const float* kptr = k + ((size_t)bh * Tt + blk * 128) * 64;
    const float* vptr = v + ((size_t)bh * Tt + blk * 128) * 64;
    const float* gkp  = gk + (size_t)bh * Gg * 64;
    const float* gvp  = gv + (size_t)bh * Gg * 64;
    const float* amp  = amask + (size_t)bh * Tt + blk * 128;
    const float* gmp  = gmask + (size_t)bh * Gg;

    // ---- Q as B-operand frags: n=c15 (q-row), k=d=32*half+quad*8+j ----
    bf16x8 qbh[2], qbl[2];
    {
        int row = wv * 16 + c15;
#pragma unroll
        for (int h = 0; h < 2; ++h) {
            f32x4 a = *(const f32x4*)(qptr + row * 64 + h * 32 + quad * 8);
            f32x4 b = *(const f32x4*)(qptr + row * 64 + h * 32 + quad * 8 + 4);
            split8v(a, b, qbh[h], qbl[h]);
        }
    }

    // ---- staging geometry (waves 0-3: K chunk; waves 4-7: V^T chunk) ----
    const int slot = tid & 15;
    const int r0k  = (tid >> 4) & 15;
    const int tV   = tid & 255;
    const int key0 = 4 * (tV & 15);
    const int d0v  = 4 * ((tV >> 4) & 3) + 16 * (tV >> 6);

    // load + convert + LDS-store chunk c; no persistent prefetch regs.
    auto stage = [&](int c) {
        if (wv < 4) {
            const float* s = (c < 2) ? (kptr + c * 4096) : (gkp + (c - 2) * 4096);
            unsigned short* kh = (unsigned short*)lds;
            unsigned short* kl = (unsigned short*)(lds + 9216);
            f32x4 t[4];
#pragma unroll
            for (int i = 0; i < 4; ++i)
                t[i] = *(const f32x4*)(s + (r0k + i * 16) * 64 + slot * 4);
#pragma unroll
            for (int i = 0; i < 4; ++i) {
                unsigned int h0, l0, h1, l1;
                split2(t[i][0], t[i][1], h0, l0);
                split2(t[i][2], t[i][3], h1, l1);
                int o = (r0k + i * 16) * 72 + slot * 4;
                *reinterpret_cast<uint2*>(kh + o) = make_uint2(h0, h1);
                *reinterpret_cast<uint2*>(kl + o) = make_uint2(l0, l1);
            }
        } else {
            const float* s = (c < 2) ? (vptr + c * 4096) : (gvp + (c - 2) * 4096);
            unsigned short* vb = (unsigned short*)(lds + 18432);
            f32x4 t[4];
#pragma unroll
            for (int j = 0; j < 4; ++j)
                t[j] = *(const f32x4*)(s + (key0 + j) * 64 + d0v);
#pragma unroll
            for (int i = 0; i < 4; ++i) {
                unsigned int h0 = cvt_pk(t[0][i], t[1][i]);
                unsigned int h1 = cvt_pk(t[2][i], t[3][i]);
                int o = (d0v + i) * 72 + key0;
                *reinterpret_cast<uint2*>(vb + o) = make_uint2(h0, h1);
            }
        }
        if (tid < 64) {
            float m = (c < 2) ? amp[c * 64 + tid] : gmp[(c - 2) * 64 + tid];
            m_lds[tid] = m * LOG2E;
        }
    };

    // ---- prologue: fill buffer with chunk 0 ----
    stage(0);
    __syncthreads();

    const f32x4 zero4 = {0.f, 0.f, 0.f, 0.f};
    f32x4 ctx[4];  // ctx^T[d=dm*16+quad*4+r][q=c15]
#pragma unroll
    for (int dm = 0; dm < 4; ++dm) ctx[dm] = zero4;
    float m_run = -3.4e38f;  // running max, log2 units
    float l_run = 0.f;       // per-lane partial; cross-quad reduce in epilogue

    const unsigned short* k_hi = (const unsigned short*)lds;
    const unsigned short* k_lo = (const unsigned short*)(lds + 9216);
    const unsigned short* v_hi = (const unsigned short*)(lds + 18432);

#pragma unroll
    for (int c = 0; c < 4; ++c) {
        // ---- S^T = K·Q^T, two passes (K-frag transients capped at 8) ----
        f32x4 S[4];
#pragma unroll
        for (int km = 0; km < 4; ++km) S[km] = zero4;

        __builtin_amdgcn_s_setprio(1);
#pragma unroll
        for (int km = 0; km < 4; ++km) {  // pass A: K_hi x (Q_hi, Q_lo)
            int krow = km * 16 + c15;
            bf16x8 kh0 = *(const bf16x8*)(k_hi + krow * 72 + quad * 8);
            bf16x8 kh1 = *(const bf16x8*)(k_hi + krow * 72 + quad * 8 + 32);
            f32x4 a = S[km];
            a = MFMA32(kh0, qbh[0], a);
            a = MFMA32(kh1, qbh[1], a);
            a = MFMA32(kh0, qbl[0], a);
            a = MFMA32(kh1, qbl[1], a);
            S[km] = a;
        }
#pragma unroll
        for (int km = 0; km < 4; ++km) {  // pass B: K_lo x Q_hi
            int krow = km * 16 + c15;
            bf16x8 kl0 = *(const bf16x8*)(k_lo + krow * 72 + quad * 8);
            bf16x8 kl1 = *(const bf16x8*)(k_lo + krow * 72 + quad * 8 + 32);
            f32x4 a = S[km];
            a = MFMA32(kl0, qbh[0], a);
            a = MFMA32(kl1, qbh[1], a);
            S[km] = a;
        }
        __builtin_amdgcn_s_setprio(0);

        // ---- online softmax, log2 domain, deferred max + deferred sum ----
        bf16x4 ph[4];
        {
            float pmax = -3.4e38f;
#pragma unroll
            for (int km = 0; km < 4; ++km) {
                // broadcast mask read, 4-reg transient
                f32x4 mkl = *(const f32x4*)(m_lds + km * 16 + quad * 4);
#pragma unroll
                for (int r = 0; r < 4; ++r) {
                    float s = fmaf(S[km][r], QSCALE, mkl[r]);
                    S[km][r] = s;
                    pmax = fmaxf(pmax, s);
                }
            }
            if (!__all(pmax <= m_run + DEFER_THR)) {
                float mx = fmaxf(pmax, __shfl_xor(pmax, 16));
                mx = fmaxf(mx, __shfl_xor(mx, 32));
                float mn = fmaxf(m_run, mx);
                float alpha = __builtin_amdgcn_exp2f(m_run - mn);
                m_run = mn;
                l_run *= alpha;
#pragma unroll
                for (int dm = 0; dm < 4; ++dm) {
                    ctx[dm][0] *= alpha; ctx[dm][1] *= alpha;
                    ctx[dm][2] *= alpha; ctx[dm][3] *= alpha;
                }
            }
            float sm = 0.f;
#pragma unroll
            for (int km = 0; km < 4; ++km) {
#pragma unroll
                for (int r = 0; r < 4; ++r) {
                    float e = __builtin_amdgcn_exp2f(S[km][r] - m_run);
                    S[km][r] = e;
                    sm += e;
                }
                union { bf16x4 b; uint2 u; } P;
                P.u.x = cvt_pk(S[km][0], S[km][1]);
                P.u.y = cvt_pk(S[km][2], S[km][3]);
                ph[km] = P.b;
            }
            l_run += sm;
        }

        // ---- ctx^T += V^T_hi · P^T (mfma 16x16x16, 16 MFMAs) ----
        __builtin_amdgcn_s_setprio(1);
#pragma unroll
        for (int dm = 0; dm < 4; ++dm) {
            int drow = dm * 16 + c15;
            f32x4 a = ctx[dm];
#pragma unroll
            for (int km = 0; km < 4; ++km) {
                bf16x4 vh = *(const bf16x4*)(v_hi + drow * 72 + km * 16 + quad * 4);
                a = MFMA16(vh, ph[km], a);
            }
            ctx[dm] = a;
        }
        __builtin_amdgcn_s_setprio(0);

        // stage next chunk; exposed latency covered by 6 waves/SIMD TLP
        if (c < 3) {
            __syncthreads();
            stage(c + 1);
            __syncthreads();
        }
    }

    // ---- epilogue: reduce l across quads, normalize, store DIRECT ----
    // ctx[dm] holds ctx^T[d = dm*16+quad*4 .. +4)[q = wv*16+c15] -> for each
    // dm the 4 floats are contiguous in d: one f32x4 store per dm.
    {
        float l = l_run;
        l += __shfl_xor(l, 16);
        l += __shfl_xor(l, 32);
        float inv = 1.0f / l;
        float* op = out + ((size_t)bh * Tt + blk * 128 + wv * 16 + c15) * 64;
#pragma unroll
        for (int dm = 0; dm < 4; ++dm) {
            f32x4 o = ctx[dm];
            o[0] *= inv; o[1] *= inv; o[2] *= inv; o[3] *= inv;
            *(f32x4*)(op + dm * 16 + quad * 4) = o;
        }
    }
}

extern "C" void kernel_launch(void* const* d_in, const int* in_sizes, int n_in,
                              void* d_out, int out_size, void* d_ws, size_t ws_size,
                              hipStream_t stream) {
    (void)in_sizes; (void)n_in; (void)d_ws; (void)ws_size; (void)out_size;
    const float* q  = (const float*)d_in[0];
    const float* k  = (const float*)d_in[1];
    const float* v  = (const float*)d_in[2];
    const float* am = (const float*)d_in[3];
    const float* gk = (const float*)d_in[4];
    const float* gv = (const float*)d_in[5];
    const float* gm = (const float*)d_in[6];
    dim3 grid(32, 16, 4);
    block_attn_kernel<<<grid, dim3(512), 0, stream>>>(q, k, v, am, gk, gv, gm, (float*)d_out);
}

// Round 10
// 245.743 us; speedup vs baseline: 1.0588x; 1.0588x over previous
//
#include <hip/hip_runtime.h>
#include <hip/hip_bf16.h>

// Flash-style block attention, MI355X gfx950. Round 14.
// R8/R9/R10/R13: four spills prove true reg need ~100-105 (VGPR ~60 + AGPR
// ~44, matches R12's no-spill at cap 128). (512,6)'s cap 84 is unreachable.
// R14 unlocks the intermediate occupancy step with 256-thread WGs:
//  - (256,5): cap = 512/5 = 102 ~= measured need -> near-fit by DATA.
//  - 4 waves/WG x 16 q-rows = 64 q-rows/WG; grid x doubles to 64; sibling
//    WGs share a parent 128-block (keys = parent's 128 local + 128 global).
//  - LDS 27904 B/WG -> 5 WGs/CU = 20 waves/CU (62%), 5 INDEPENDENT WGs
//    (vs 2) breaks barrier lockstep. +25% TLP over R12.
//  - Cost: sibling re-stages K/V (FETCH ~115->~240MB, HBM 23->~45%, slack);
//    per-thread staging doubles (does both K and V parts; VALU has room).
//  - Compute loop = R12/R13: two-pass QK, masks in LDS, defer-max, exp2,
//    P single-bf16, V hi-only, direct-to-global epilogue, no reg prefetch.
// Predicted: WRITE=65536KB exactly (spill test), dur ~80-85us/dispatch,
// Occ ~60%, VGPR ~55, MfmaUtil ~21, VALU ~38, conflicts ~17M.

typedef __attribute__((ext_vector_type(8))) short bf16x8;
typedef __attribute__((ext_vector_type(4))) short bf16x4;
typedef __attribute__((ext_vector_type(4))) float f32x4;

#define MFMA32(A, B, C) __builtin_amdgcn_mfma_f32_16x16x32_bf16((A), (B), (C), 0, 0, 0)
#define MFMA16(A, B, C) __builtin_amdgcn_mfma_f32_16x16x16bf16_1k((A), (B), (C), 0, 0, 0)

__device__ __forceinline__ unsigned int cvt_pk(float a, float b) {
    __hip_bfloat162 h = __float22bfloat162_rn(float2{a, b});
    union { __hip_bfloat162 h; unsigned int u; } c;
    c.h = h;
    return c.u;
}
__device__ __forceinline__ void split2(float a, float b, unsigned int& hi, unsigned int& lo) {
    unsigned int h = cvt_pk(a, b);
    float ra = a - __uint_as_float(h << 16);
    float rb = b - __uint_as_float(h & 0xFFFF0000u);
    hi = h;
    lo = cvt_pk(ra, rb);
}
__device__ __forceinline__ void split8v(f32x4 a, f32x4 b, bf16x8& hi, bf16x8& lo) {
    union { bf16x8 v; unsigned int w[4]; } H, L;
    split2(a[0], a[1], H.w[0], L.w[0]);
    split2(a[2], a[3], H.w[1], L.w[1]);
    split2(b[0], b[1], H.w[2], L.w[2]);
    split2(b[2], b[3], H.w[3], L.w[3]);
    hi = H.v; lo = L.v;
}

// LDS: K_hi [64][72] hw (9216) | K_lo [64][72] hw (9216) | V^T [64][72] hw
// (9216) | mask*log2e [64] f32 (256) = 27904 B.
#define LDS_BYTES 27904

#define LOG2E 1.44269504f
#define QSCALE 0.180336880f  /* 0.125 * log2(e) */
#define DEFER_THR 8.0f

__global__ __launch_bounds__(256, 5) void block_attn_kernel(
    const float* __restrict__ q, const float* __restrict__ k,
    const float* __restrict__ v, const float* __restrict__ amask,
    const float* __restrict__ gk, const float* __restrict__ gv,
    const float* __restrict__ gmask, float* __restrict__ out) {
    constexpr int Hh = 16, Tt = 4096, Gg = 128;

    __shared__ __align__(16) unsigned char lds[LDS_BYTES];
    float* m_lds = (float*)(lds + 27648);  // [64] mask * log2e

    const int blk = blockIdx.x;            // 0..63: 64-row q sub-block
    const int par = blk >> 1;              // parent 128-row block
    const int bh  = blockIdx.z * Hh + blockIdx.y;
    const int tid  = threadIdx.x;          // 0..255
    const int lane = tid & 63;
    const int wv   = tid >> 6;             // 0..3, wave owns q-rows [wv*16,+16)
    const int c15  = lane & 15;
    const int quad = lane >> 4;

    const float* qptr = q + ((size_t)bh * Tt + blk * 64) * 64;
    const float* kptr = k + ((size_t)bh * Tt + par * 128) * 64;
    const float* vptr = v + ((size_t)bh * Tt + par * 128) * 64;
    const float* gkp  = gk + (size_t)bh * Gg * 64;
    const float* gvp  = gv + (size_t)bh * Gg * 64;
    const float* amp  = amask + (size_t)bh * Tt + par * 128;
    const float* gmp  = gmask + (size_t)bh * Gg;

    // ---- Q as B-operand frags: n=c15 (q-row), k=d=32*half+quad*8+j ----
    bf16x8 qbh[2], qbl[2];
    {
        int row = wv * 16 + c15;
#pragma unroll
        for (int h = 0; h < 2; ++h) {
            f32x4 a = *(const f32x4*)(qptr + row * 64 + h * 32 + quad * 8);
            f32x4 b = *(const f32x4*)(qptr + row * 64 + h * 32 + quad * 8 + 4);
            split8v(a, b, qbh[h], qbl[h]);
        }
    }

    // ---- staging geometry: every thread does K part AND V part ----
    const int slot = tid & 15;             // K: d-col group
    const int r0k  = tid >> 4;             // K: key row 0..15
    const int key0 = 4 * (tid & 15);       // V: key group
    const int d0v  = 4 * ((tid >> 4) & 3) + 16 * (tid >> 6);  // V: d row

    auto stage = [&](int c) {
        {   // K -> hi/lo split
            const float* s = (c < 2) ? (kptr + c * 4096) : (gkp + (c - 2) * 4096);
            unsigned short* kh = (unsigned short*)lds;
            unsigned short* kl = (unsigned short*)(lds + 9216);
            f32x4 t[4];
#pragma unroll
            for (int i = 0; i < 4; ++i)
                t[i] = *(const f32x4*)(s + (r0k + i * 16) * 64 + slot * 4);
#pragma unroll
            for (int i = 0; i < 4; ++i) {
                unsigned int h0, l0, h1, l1;
                split2(t[i][0], t[i][1], h0, l0);
                split2(t[i][2], t[i][3], h1, l1);
                int o = (r0k + i * 16) * 72 + slot * 4;
                *reinterpret_cast<uint2*>(kh + o) = make_uint2(h0, h1);
                *reinterpret_cast<uint2*>(kl + o) = make_uint2(l0, l1);
            }
        }
        {   // V^T -> single bf16
            const float* s = (c < 2) ? (vptr + c * 4096) : (gvp + (c - 2) * 4096);
            unsigned short* vb = (unsigned short*)(lds + 18432);
            f32x4 t[4];
#pragma unroll
            for (int j = 0; j < 4; ++j)
                t[j] = *(const f32x4*)(s + (key0 + j) * 64 + d0v);
#pragma unroll
            for (int i = 0; i < 4; ++i) {
                unsigned int h0 = cvt_pk(t[0][i], t[1][i]);
                unsigned int h1 = cvt_pk(t[2][i], t[3][i]);
                int o = (d0v + i) * 72 + key0;
                *reinterpret_cast<uint2*>(vb + o) = make_uint2(h0, h1);
            }
        }
        if (tid < 64) {
            float m = (c < 2) ? amp[c * 64 + tid] : gmp[(c - 2) * 64 + tid];
            m_lds[tid] = m * LOG2E;
        }
    };

    // ---- prologue: fill buffer with chunk 0 ----
    stage(0);
    __syncthreads();

    const f32x4 zero4 = {0.f, 0.f, 0.f, 0.f};
    f32x4 ctx[4];  // ctx^T[d=dm*16+quad*4+r][q=c15]
#pragma unroll
    for (int dm = 0; dm < 4; ++dm) ctx[dm] = zero4;
    float m_run = -3.4e38f;  // running max, log2 units
    float l_run = 0.f;       // per-lane partial; cross-quad reduce in epilogue

    const unsigned short* k_hi = (const unsigned short*)lds;
    const unsigned short* k_lo = (const unsigned short*)(lds + 9216);
    const unsigned short* v_hi = (const unsigned short*)(lds + 18432);

#pragma unroll
    for (int c = 0; c < 4; ++c) {
        // ---- S^T = K·Q^T, two passes (K-frag transients capped at 8) ----
        f32x4 S[4];
#pragma unroll
        for (int km = 0; km < 4; ++km) S[km] = zero4;

        __builtin_amdgcn_s_setprio(1);
#pragma unroll
        for (int km = 0; km < 4; ++km) {  // pass A: K_hi x (Q_hi, Q_lo)
            int krow = km * 16 + c15;
            bf16x8 kh0 = *(const bf16x8*)(k_hi + krow * 72 + quad * 8);
            bf16x8 kh1 = *(const bf16x8*)(k_hi + krow * 72 + quad * 8 + 32);
            f32x4 a = S[km];
            a = MFMA32(kh0, qbh[0], a);
            a = MFMA32(kh1, qbh[1], a);
            a = MFMA32(kh0, qbl[0], a);
            a = MFMA32(kh1, qbl[1], a);
            S[km] = a;
        }
#pragma unroll
        for (int km = 0; km < 4; ++km) {  // pass B: K_lo x Q_hi
            int krow = km * 16 + c15;
            bf16x8 kl0 = *(const bf16x8*)(k_lo + krow * 72 + quad * 8);
            bf16x8 kl1 = *(const bf16x8*)(k_lo + krow * 72 + quad * 8 + 32);
            f32x4 a = S[km];
            a = MFMA32(kl0, qbh[0], a);
            a = MFMA32(kl1, qbh[1], a);
            S[km] = a;
        }
        __builtin_amdgcn_s_setprio(0);

        // ---- online softmax, log2 domain, deferred max + deferred sum ----
        bf16x4 ph[4];
        {
            float pmax = -3.4e38f;
#pragma unroll
            for (int km = 0; km < 4; ++km) {
                f32x4 mkl = *(const f32x4*)(m_lds + km * 16 + quad * 4);
#pragma unroll
                for (int r = 0; r < 4; ++r) {
                    float s = fmaf(S[km][r], QSCALE, mkl[r]);
                    S[km][r] = s;
                    pmax = fmaxf(pmax, s);
                }
            }
            if (!__all(pmax <= m_run + DEFER_THR)) {
                float mx = fmaxf(pmax, __shfl_xor(pmax, 16));
                mx = fmaxf(mx, __shfl_xor(mx, 32));
                float mn = fmaxf(m_run, mx);
                float alpha = __builtin_amdgcn_exp2f(m_run - mn);
                m_run = mn;
                l_run *= alpha;
#pragma unroll
                for (int dm = 0; dm < 4; ++dm) {
                    ctx[dm][0] *= alpha; ctx[dm][1] *= alpha;
                    ctx[dm][2] *= alpha; ctx[dm][3] *= alpha;
                }
            }
            float sm = 0.f;
#pragma unroll
            for (int km = 0; km < 4; ++km) {
#pragma unroll
                for (int r = 0; r < 4; ++r) {
                    float e = __builtin_amdgcn_exp2f(S[km][r] - m_run);
                    S[km][r] = e;
                    sm += e;
                }
                union { bf16x4 b; uint2 u; } P;
                P.u.x = cvt_pk(S[km][0], S[km][1]);
                P.u.y = cvt_pk(S[km][2], S[km][3]);
                ph[km] = P.b;
            }
            l_run += sm;
        }

        // ---- ctx^T += V^T_hi · P^T (mfma 16x16x16, 16 MFMAs) ----
        __builtin_amdgcn_s_setprio(1);
#pragma unroll
        for (int dm = 0; dm < 4; ++dm) {
            int drow = dm * 16 + c15;
            f32x4 a = ctx[dm];
#pragma unroll
            for (int km = 0; km < 4; ++km) {
                bf16x4 vh = *(const bf16x4*)(v_hi + drow * 72 + km * 16 + quad * 4);
                a = MFMA16(vh, ph[km], a);
            }
            ctx[dm] = a;
        }
        __builtin_amdgcn_s_setprio(0);

        // stage next chunk; exposed latency covered by 5 independent WGs/CU
        if (c < 3) {
            __syncthreads();
            stage(c + 1);
            __syncthreads();
        }
    }

    // ---- epilogue: reduce l across quads, normalize, store DIRECT ----
    {
        float l = l_run;
        l += __shfl_xor(l, 16);
        l += __shfl_xor(l, 32);
        float inv = 1.0f / l;
        float* op = out + ((size_t)bh * Tt + blk * 64 + wv * 16 + c15) * 64;
#pragma unroll
        for (int dm = 0; dm < 4; ++dm) {
            f32x4 o = ctx[dm];
            o[0] *= inv; o[1] *= inv; o[2] *= inv; o[3] *= inv;
            *(f32x4*)(op + dm * 16 + quad * 4) = o;
        }
    }
}

extern "C" void kernel_launch(void* const* d_in, const int* in_sizes, int n_in,
                              void* d_out, int out_size, void* d_ws, size_t ws_size,
                              hipStream_t stream) {
    (void)in_sizes; (void)n_in; (void)d_ws; (void)ws_size; (void)out_size;
    const float* q  = (const float*)d_in[0];
    const float* k  = (const float*)d_in[1];
    const float* v  = (const float*)d_in[2];
    const float* am = (const float*)d_in[3];
    const float* gk = (const float*)d_in[4];
    const float* gv = (const float*)d_in[5];
    const float* gm = (const float*)d_in[6];
    dim3 grid(64, 16, 4);
    block_attn_kernel<<<grid, dim3(256), 0, stream>>>(q, k, v, am, gk, gv, gm, (float*)d_out);
}